// Round 1
// baseline (4558.396 us; speedup 1.0000x reference)
//
#include <hip/hip_runtime.h>
#include <hip/hip_bf16.h>
#include <stdint.h>

// ACT (adaptive computation time) on MI355X.
// fp32 compute throughout (halting decisions q>0.99 need ~1e-6 reproducibility
// vs the numpy fp32 reference -> bf16 MFMA would flip ~10 positions' halting
// step and fail n_updates). Halted positions are skipped via per-iteration
// compaction (active list built by the ponder kernel).
// Dtype (bf16 vs fp32 in/out) is detected at runtime from mask[0] bits.

#define THR (1.0f - 0.01f)
typedef float4 f4;

__device__ __forceinline__ float ld_in(const void* p, long i, int bf) {
  if (bf) {
    unsigned short u = ((const unsigned short*)p)[i];
    return __uint_as_float(((unsigned int)u) << 16);
  }
  return ((const float*)p)[i];
}
__device__ __forceinline__ f4 ld4(const float* p) { return *(const f4*)p; }

#define ADD4(d, s, e) \
  d.x = s.x + e.x; d.y = s.y + e.y; d.z = s.z + e.z; d.w = s.w + e.w;

// ---------- dtype detect + small param conversion ----------
__global__ void k_detect(const void* mask, int* flag, const void* emb,
                         const void* Wp, const void* bp, const void* b1,
                         const void* b2, float* embF, float* WpF, float* bpF,
                         float* b1F, float* b2F) {
  __shared__ int sbf;
  if (threadIdx.x == 0) {
    unsigned int u = ((const unsigned int*)mask)[0];
    int bf = (u == 0x3F803F80u) ? 1 : 0;  // two bf16 1.0s vs fp32 1.0
    *flag = bf;
    sbf = bf;
  }
  __syncthreads();
  int bf = sbf;
  for (int i = threadIdx.x; i < 11 * 512; i += 256) embF[i] = ld_in(emb, i, bf);
  for (int i = threadIdx.x; i < 512; i += 256) WpF[i] = ld_in(Wp, i, bf);
  for (int i = threadIdx.x; i < 2048; i += 256) b1F[i] = ld_in(b1, i, bf);
  for (int i = threadIdx.x; i < 512; i += 256) b2F[i] = ld_in(b2, i, bf);
  if (threadIdx.x == 0) bpF[0] = ld_in(bp, 0, bf);
}

// ---------- big conversions + zero init ----------
__global__ void k_init(const void* state, const void* W1, const void* W2,
                       const void* mask, const int* flag, float* stateF,
                       float* W1F, float* W2F, float* maskF, float* prevF,
                       float* hp, float* rem, float* nup, int* counts) {
  int bf = *flag;
  long t = (long)blockIdx.x * blockDim.x + threadIdx.x;
  long st = (long)gridDim.x * blockDim.x;
  for (long i = t; i < 8388608L; i += st) {
    stateF[i] = ld_in(state, i, bf);
    prevF[i] = 0.f;
  }
  for (long i = t; i < 1048576L; i += st) {
    W1F[i] = ld_in(W1, i, bf);
    W2F[i] = ld_in(W2, i, bf);
  }
  for (long i = t; i < 16384L; i += st) {
    maskF[i] = ld_in(mask, i, bf);
    hp[i] = 0.f;
    rem[i] = 0.f;
    nup[i] = 0.f;
  }
  if (t < 11) counts[t] = 0;
}

// ---------- pondering + halting update + compaction (1 wave / position) ----
__global__ __launch_bounds__(256) void k_ponder(
    const float* __restrict__ stateF, const float* __restrict__ embF,
    const float* __restrict__ WpF, const float* __restrict__ bpF, float* hp,
    float* rem, float* nup, float* uw, int* __restrict__ count,
    int* __restrict__ ridx, int t) {
  int lane = threadIdx.x & 63;
  int pos = blockIdx.x * 4 + (threadIdx.x >> 6);
  float hpv = hp[pos];
  if (hpv >= 1.0f) return;  // halted forever: nothing can change
  const float* s = stateF + (long)pos * 512;
  const float* e = embF + t * 512;
  int d = lane * 8;
  f4 s0 = ld4(s + d), s1 = ld4(s + d + 4);
  f4 e0 = ld4(e + d), e1 = ld4(e + d + 4);
  f4 w0 = ld4(WpF + d), w1 = ld4(WpF + d + 4);
  float acc = (s0.x + e0.x) * w0.x;
  acc = fmaf(s0.y + e0.y, w0.y, acc);
  acc = fmaf(s0.z + e0.z, w0.z, acc);
  acc = fmaf(s0.w + e0.w, w0.w, acc);
  acc = fmaf(s1.x + e1.x, w1.x, acc);
  acc = fmaf(s1.y + e1.y, w1.y, acc);
  acc = fmaf(s1.z + e1.z, w1.z, acc);
  acc = fmaf(s1.w + e1.w, w1.w, acc);
#pragma unroll
  for (int off = 32; off > 0; off >>= 1) acc += __shfl_xor(acc, off, 64);
  if (lane == 0) {
    float p = 1.0f / (1.0f + expf(-(acc + bpF[0])));
    // exact fp32 mirror of the reference's scalar chain (still==1 here)
    float q = hpv + p;
    float nh = (q > THR) ? 1.0f : 0.0f;
    float st2 = (q <= THR) ? 1.0f : 0.0f;
    float hpn = hpv + p * st2;
    float remn = rem[pos] + nh * (1.0f - hpn);
    hpn = hpn + nh * remn;
    nup[pos] = nup[pos] + st2 + nh;
    uw[pos] = p * st2 + nh * remn;
    hp[pos] = hpn;
    rem[pos] = remn;
    int idx = atomicAdd(count, 1);
    ridx[idx] = pos;
  }
}

#define STORE_TILE(buf)                                                        \
  As[buf][kq4 + 0][ra] = a0.x; As[buf][kq4 + 1][ra] = a0.y;                    \
  As[buf][kq4 + 2][ra] = a0.z; As[buf][kq4 + 3][ra] = a0.w;                    \
  As[buf][kq4 + 0][ra + 64] = a1.x; As[buf][kq4 + 1][ra + 64] = a1.y;          \
  As[buf][kq4 + 2][ra + 64] = a1.z; As[buf][kq4 + 3][ra + 64] = a1.w;          \
  *(f4*)&Bs[buf][kb1][nb] = b0; *(f4*)&Bs[buf][kb2][nb] = b1;

#define FMA_BLOCK(cur)                                                         \
  _Pragma("unroll") for (int k = 0; k < 16; k++) {                             \
    float av[8], bv[8];                                                        \
    *(f4*)(av + 0) = *(const f4*)&As[cur][k][ty * 8];                          \
    *(f4*)(av + 4) = *(const f4*)&As[cur][k][ty * 8 + 4];                      \
    *(f4*)(bv + 0) = *(const f4*)&Bs[cur][k][tx * 8];                          \
    *(f4*)(bv + 4) = *(const f4*)&Bs[cur][k][tx * 8 + 4];                      \
    _Pragma("unroll") for (int i = 0; i < 8; i++)                              \
        _Pragma("unroll") for (int j = 0; j < 8; j++) acc[i][j] =              \
        fmaf(av[i], bv[j], acc[i][j]);                                         \
  }

// ---------- GEMM1: U = relu((state[ridx]+emb) * W1 + b1), K=512, N=2048 ----
__global__ __launch_bounds__(256) void k_gemm1(
    const float* __restrict__ stateF, const float* __restrict__ embT,
    const float* __restrict__ W, const float* __restrict__ bias,
    const int* __restrict__ count, const int* __restrict__ ridx,
    float* __restrict__ U, int c0, int mc) {
  const int NN = 2048, KT = 32;
  int Ma = *count;
  int mEnd = c0 + mc;
  if (Ma < mEnd) mEnd = Ma;
  int m0 = c0 + blockIdx.x * 128;
  if (m0 >= mEnd) return;
  int n0 = blockIdx.y * 128;
  __shared__ float As[2][16][128];
  __shared__ float Bs[2][16][128];
  int tid = threadIdx.x;
  int ra = tid >> 2;
  int kq4 = (tid & 3) << 2;
  int r1 = m0 + ra, r2 = r1 + 64;
  long p1 = (r1 < mEnd) ? (long)ridx[r1] : -1;
  long p2 = (r2 < mEnd) ? (long)ridx[r2] : -1;
  int kb1 = tid >> 5, kb2 = kb1 + 8;
  int nb = (tid & 31) << 2;
  const float* Bp = W + n0 + nb;
  f4 a0, a1, b0, b1;
  f4 zero = make_float4(0.f, 0.f, 0.f, 0.f);
  {
    f4 e = ld4(embT + kq4);
    a0 = zero; a1 = zero;
    if (p1 >= 0) { f4 s = ld4(stateF + p1 * 512 + kq4); ADD4(a0, s, e); }
    if (p2 >= 0) { f4 s = ld4(stateF + p2 * 512 + kq4); ADD4(a1, s, e); }
    b0 = ld4(Bp + (long)kb1 * NN);
    b1 = ld4(Bp + (long)kb2 * NN);
  }
  STORE_TILE(0);
  __syncthreads();
  float acc[8][8];
#pragma unroll
  for (int i = 0; i < 8; i++)
#pragma unroll
    for (int j = 0; j < 8; j++) acc[i][j] = 0.f;
  int tx = tid & 15, ty = tid >> 4;
#pragma unroll 1
  for (int kt = 0; kt < KT; ++kt) {
    int cur = kt & 1, nxt = cur ^ 1;
    if (kt + 1 < KT) {
      int kg = ((kt + 1) << 4) + kq4;
      f4 e = ld4(embT + kg);
      a0 = zero; a1 = zero;
      if (p1 >= 0) { f4 s = ld4(stateF + p1 * 512 + kg); ADD4(a0, s, e); }
      if (p2 >= 0) { f4 s = ld4(stateF + p2 * 512 + kg); ADD4(a1, s, e); }
      b0 = ld4(Bp + (long)(((kt + 1) << 4) + kb1) * NN);
      b1 = ld4(Bp + (long)(((kt + 1) << 4) + kb2) * NN);
    }
    FMA_BLOCK(cur);
    if (kt + 1 < KT) { STORE_TILE(nxt); }
    __syncthreads();
  }
  f4 bb0 = ld4(bias + n0 + tx * 8);
  f4 bb1 = ld4(bias + n0 + tx * 8 + 4);
#pragma unroll
  for (int i = 0; i < 8; i++) {
    int r = m0 + ty * 8 + i;
    if (r < mEnd) {
      float* dst = U + (long)(r - c0) * 2048 + n0 + tx * 8;
      f4 o0, o1;
      o0.x = fmaxf(acc[i][0] + bb0.x, 0.f);
      o0.y = fmaxf(acc[i][1] + bb0.y, 0.f);
      o0.z = fmaxf(acc[i][2] + bb0.z, 0.f);
      o0.w = fmaxf(acc[i][3] + bb0.w, 0.f);
      o1.x = fmaxf(acc[i][4] + bb1.x, 0.f);
      o1.y = fmaxf(acc[i][5] + bb1.y, 0.f);
      o1.z = fmaxf(acc[i][6] + bb1.z, 0.f);
      o1.w = fmaxf(acc[i][7] + bb1.w, 0.f);
      *(f4*)dst = o0;
      *(f4*)(dst + 4) = o1;
    }
  }
}

// ---------- GEMM2: h = U*W2 + b2; state=h*mask; prev += h*uw. K=2048,N=512 --
__global__ __launch_bounds__(256) void k_gemm2(
    const float* __restrict__ U, const float* __restrict__ W,
    const float* __restrict__ bias, const int* __restrict__ count,
    const int* __restrict__ ridx, const float* __restrict__ maskF,
    const float* __restrict__ uwF, float* __restrict__ stateF,
    float* __restrict__ prevF, int c0, int mc) {
  const int NN = 512, KT = 128;
  int Ma = *count;
  int mEnd = c0 + mc;
  if (Ma < mEnd) mEnd = Ma;
  int m0 = c0 + blockIdx.x * 128;
  if (m0 >= mEnd) return;
  int n0 = blockIdx.y * 128;
  __shared__ float As[2][16][128];
  __shared__ float Bs[2][16][128];
  int tid = threadIdx.x;
  int ra = tid >> 2;
  int kq4 = (tid & 3) << 2;
  int r1 = m0 + ra, r2 = r1 + 64;
  long q1 = (r1 < mEnd) ? (long)(r1 - c0) : -1;
  long q2 = (r2 < mEnd) ? (long)(r2 - c0) : -1;
  int kb1 = tid >> 5, kb2 = kb1 + 8;
  int nb = (tid & 31) << 2;
  const float* Bp = W + n0 + nb;
  f4 a0, a1, b0, b1;
  f4 zero = make_float4(0.f, 0.f, 0.f, 0.f);
  {
    a0 = (q1 >= 0) ? ld4(U + q1 * 2048 + kq4) : zero;
    a1 = (q2 >= 0) ? ld4(U + q2 * 2048 + kq4) : zero;
    b0 = ld4(Bp + (long)kb1 * NN);
    b1 = ld4(Bp + (long)kb2 * NN);
  }
  STORE_TILE(0);
  __syncthreads();
  float acc[8][8];
#pragma unroll
  for (int i = 0; i < 8; i++)
#pragma unroll
    for (int j = 0; j < 8; j++) acc[i][j] = 0.f;
  int tx = tid & 15, ty = tid >> 4;
#pragma unroll 1
  for (int kt = 0; kt < KT; ++kt) {
    int cur = kt & 1, nxt = cur ^ 1;
    if (kt + 1 < KT) {
      int kg = ((kt + 1) << 4) + kq4;
      a0 = (q1 >= 0) ? ld4(U + q1 * 2048 + kg) : zero;
      a1 = (q2 >= 0) ? ld4(U + q2 * 2048 + kg) : zero;
      b0 = ld4(Bp + (long)(((kt + 1) << 4) + kb1) * NN);
      b1 = ld4(Bp + (long)(((kt + 1) << 4) + kb2) * NN);
    }
    FMA_BLOCK(cur);
    if (kt + 1 < KT) { STORE_TILE(nxt); }
    __syncthreads();
  }
  f4 bb0 = ld4(bias + n0 + tx * 8);
  f4 bb1 = ld4(bias + n0 + tx * 8 + 4);
#pragma unroll
  for (int i = 0; i < 8; i++) {
    int r = m0 + ty * 8 + i;
    if (r < mEnd) {
      long pos = (long)ridx[r];
      float mk = maskF[pos];
      float uv = uwF[pos];
      float* sp = stateF + pos * 512 + n0 + tx * 8;
      float* pp = prevF + pos * 512 + n0 + tx * 8;
      f4 h0, h1;
      h0.x = (acc[i][0] + bb0.x) * mk;
      h0.y = (acc[i][1] + bb0.y) * mk;
      h0.z = (acc[i][2] + bb0.z) * mk;
      h0.w = (acc[i][3] + bb0.w) * mk;
      h1.x = (acc[i][4] + bb1.x) * mk;
      h1.y = (acc[i][5] + bb1.y) * mk;
      h1.z = (acc[i][6] + bb1.z) * mk;
      h1.w = (acc[i][7] + bb1.w) * mk;
      f4 p0 = ld4(pp), p1v = ld4(pp + 4);
      p0.x = fmaf(h0.x, uv, p0.x);
      p0.y = fmaf(h0.y, uv, p0.y);
      p0.z = fmaf(h0.z, uv, p0.z);
      p0.w = fmaf(h0.w, uv, p0.w);
      p1v.x = fmaf(h1.x, uv, p1v.x);
      p1v.y = fmaf(h1.y, uv, p1v.y);
      p1v.z = fmaf(h1.z, uv, p1v.z);
      p1v.w = fmaf(h1.w, uv, p1v.w);
      *(f4*)sp = h0;
      *(f4*)(sp + 4) = h1;
      *(f4*)pp = p0;
      *(f4*)(pp + 4) = p1v;
    }
  }
}

// ---------- final: concat outputs, cast per detected dtype ----------
__global__ void k_final(const float* prevF, const float* nupF,
                        const float* remF, void* out, const int* flag) {
  long i = (long)blockIdx.x * 256 + threadIdx.x;
  if (i >= 8421376L) return;
  float v;
  if (i < 8388608L) v = prevF[i];
  else if (i < 8404992L) v = nupF[i - 8388608L];
  else v = remF[i - 8404992L];
  if (*flag) ((__hip_bfloat16*)out)[i] = __float2bfloat16(v);
  else ((float*)out)[i] = v;
}

extern "C" void kernel_launch(void* const* d_in, const int* in_sizes, int n_in,
                              void* d_out, int out_size, void* d_ws,
                              size_t ws_size, hipStream_t stream) {
  const void* state = d_in[0];
  const void* mask = d_in[1];
  const void* emb = d_in[2];
  const void* Wp = d_in[3];
  const void* bp = d_in[4];
  const void* W1 = d_in[5];
  const void* b1 = d_in[6];
  const void* W2 = d_in[7];
  const void* b2 = d_in[8];
  char* w = (char*)d_ws;
  float* stateF = (float*)(w + 0L);
  float* prevF = (float*)(w + 33554432L);
  float* W1F = (float*)(w + 67108864L);
  float* W2F = (float*)(w + 71303168L);
  float* maskF = (float*)(w + 75497472L);
  float* hp = (float*)(w + 75563008L);
  float* rem = (float*)(w + 75628544L);
  float* nup = (float*)(w + 75694080L);
  float* uwf = (float*)(w + 75759616L);
  float* embF = (float*)(w + 75825152L);
  float* WpF = (float*)(w + 75849728L);
  float* b1F = (float*)(w + 75851776L);
  float* b2F = (float*)(w + 75859968L);
  float* bpF = (float*)(w + 75862016L);
  int* flag = (int*)(w + 75862272L);
  int* counts = (int*)(w + 75862528L);
  int* ridx = (int*)(w + 75863552L);
  float* U = (float*)(w + 76584448L);
  // U chunk size from remaining workspace (multiple of 128 rows of 2048 fp32)
  long ub = (long)ws_size - 76584448L;
  long rows = ub / (2048L * 4L);
  long McL = rows & ~127L;
  if (McL > 16384L) McL = 16384L;
  if (McL < 128L) McL = 128L;
  int Mc = (int)McL;
  int nCh = (16384 + Mc - 1) / Mc;

  k_detect<<<1, 256, 0, stream>>>(mask, flag, emb, Wp, bp, b1, b2, embF, WpF,
                                  bpF, b1F, b2F);
  k_init<<<2048, 256, 0, stream>>>(state, W1, W2, mask, flag, stateF, W1F, W2F,
                                   maskF, prevF, hp, rem, nup, counts);
  for (int t = 0; t <= 10; t++) {
    k_ponder<<<4096, 256, 0, stream>>>(stateF, embF, WpF, bpF, hp, rem, nup,
                                       uwf, counts + t, ridx + (long)t * 16384,
                                       t);
    for (int c = 0; c < nCh; c++) {
      int c0 = c * Mc;
      int mc = 16384 - c0;
      if (mc > Mc) mc = Mc;
      dim3 g1(mc / 128, 16), g2(mc / 128, 4);
      k_gemm1<<<g1, 256, 0, stream>>>(stateF, embF + t * 512, W1F, b1F,
                                      counts + t, ridx + (long)t * 16384, U, c0,
                                      mc);
      k_gemm2<<<g2, 256, 0, stream>>>(U, W2F, b2F, counts + t,
                                      ridx + (long)t * 16384, maskF, uwf,
                                      stateF, prevF, c0, mc);
    }
  }
  k_final<<<32896, 256, 0, stream>>>(prevF, nup, rem, d_out, flag);
}